// Round 6
// baseline (237.148 us; speedup 1.0000x reference)
//
#include <hip/hip_runtime.h>
#include <math.h>

// x: (16, 512, 512, 8) float32 NHWC. float4 granule idx:
//   idx = ((n*512 + h)*512 + w)*2 + c4
// One output granule per thread, all 9 stencil loads issued branchlessly.
// NEW vs round 5: __builtin_amdgcn_sched_barrier(0) after the load pack —
// the compiler was provably (VGPR=20) collapsing the 9-deep load window
// into 2-3-deep load->waitcnt->fmax chains to save registers, killing
// per-wave MLP. The fence forces all 9 global_load_dwordx4 in flight.

constexpr int Hdim = 512;
constexpr int Wdim = 512;
constexpr int ROWG = Wdim * 2;   // granules per image row

__device__ __forceinline__ float4 f4max(float4 a, float4 b) {
    return make_float4(fmaxf(a.x,b.x), fmaxf(a.y,b.y), fmaxf(a.z,b.z), fmaxf(a.w,b.w));
}

__global__ __launch_bounds__(256) void nms_kernel(
    const float4* __restrict__ x,
    const unsigned char* __restrict__ mask_bytes,
    float4* __restrict__ out,
    int total4)
{
    // ---- Decode 3x3 boolean mask robustly (int32 vs 1-byte bool layout).
    const int* mi = (const int*)mask_bytes;
    bool intlay = true;
    #pragma unroll
    for (int i = 0; i < 9; ++i) { int v = mi[i]; intlay = intlay && (v == 0 || v == 1); }
    bool m[9];
    #pragma unroll
    for (int i = 0; i < 9; ++i) m[i] = intlay ? (mi[i] != 0) : (mask_bytes[i] != 0);

    int idx = blockIdx.x * blockDim.x + threadIdx.x;
    if (idx >= total4) return;

    int w = (idx >> 1) & (Wdim - 1);
    int h = (idx >> 10) & (Hdim - 1);

    bool hup = (h > 0), hdn = (h < Hdim - 1);
    bool wlf = (w > 0), wrt = (w < Wdim - 1);
    int oN = hup ? -ROWG : 0;
    int oS = hdn ?  ROWG : 0;
    int oW = wlf ? -2 : 0;
    int oE = wrt ?  2 : 0;

    // ---- Issue all 9 loads; fence so none is consumed before all issue.
    __builtin_amdgcn_sched_barrier(0);
    float4 vNW = x[idx + oN + oW];
    float4 vN  = x[idx + oN];
    float4 vNE = x[idx + oN + oE];
    float4 vW  = x[idx + oW];
    float4 vC  = x[idx];
    float4 vE  = x[idx + oE];
    float4 vSW = x[idx + oS + oW];
    float4 vS  = x[idx + oS];
    float4 vSE = x[idx + oS + oE];
    __builtin_amdgcn_sched_barrier(0);

    bool k0 = m[0] && hup && wlf;
    bool k1 = m[1] && hup;
    bool k2 = m[2] && hup && wrt;
    bool k3 = m[3] && wlf;
    bool k4 = m[4];
    bool k5 = m[5] && wrt;
    bool k6 = m[6] && hdn && wlf;
    bool k7 = m[7] && hdn;
    bool k8 = m[8] && hdn && wrt;

    const float4 NEG = make_float4(-INFINITY, -INFINITY, -INFINITY, -INFINITY);
    float4 mm = NEG;
    if (k0) mm = f4max(mm, vNW);
    if (k1) mm = f4max(mm, vN);
    if (k2) mm = f4max(mm, vNE);
    if (k3) mm = f4max(mm, vW);
    if (k4) mm = f4max(mm, vC);
    if (k5) mm = f4max(mm, vE);
    if (k6) mm = f4max(mm, vSW);
    if (k7) mm = f4max(mm, vS);
    if (k8) mm = f4max(mm, vSE);

    float4 o;
    o.x = (vC.x > mm.x) ? vC.x : 0.0f;
    o.y = (vC.y > mm.y) ? vC.y : 0.0f;
    o.z = (vC.z > mm.z) ? vC.z : 0.0f;
    o.w = (vC.w > mm.w) ? vC.w : 0.0f;
    out[idx] = o;
}

extern "C" void kernel_launch(void* const* d_in, const int* in_sizes, int n_in,
                              void* d_out, int out_size, void* d_ws, size_t ws_size,
                              hipStream_t stream) {
    const float4* x = (const float4*)d_in[0];
    const unsigned char* mask = (const unsigned char*)d_in[1];
    float4* out = (float4*)d_out;

    int total4 = out_size / 4;               // 8,388,608
    int block = 256;
    int grid = (total4 + block - 1) / block; // 32768 blocks
    nms_kernel<<<grid, block, 0, stream>>>(x, mask, out, total4);
}